// Round 2
// baseline (553.579 us; speedup 1.0000x reference)
//
#include <hip/hip_runtime.h>

// ScannedLSTM: B=512, T=512, F=64, H=64 (4H=256)
// Phase 1 (zgemm): Z[bt][p] = bias + x@Wi via bf16 MFMA, p = col*4 + gate
//   (transposed GEMM: M = permuted gate index p, N = bt) -> d_ws (f32 or bf16).
// Phase 2 (recur): one wave per batch row. Lane j owns h-column j:
//   Wh columns for all 4 gates in 256 VGPRs, h broadcast via v_readlane,
//   gates computed lane-locally, no LDS, no barriers. Reset skips h@Wh.

typedef __attribute__((ext_vector_type(8))) short short8;
typedef __attribute__((ext_vector_type(4))) float f32x4;

#define NB 512
#define NT 512
#define NF 64
#define NH 64
#define NG 256
#define TCHUNK 32

__device__ __forceinline__ float rcp_fast(float x) { return __builtin_amdgcn_rcpf(x); }
__device__ __forceinline__ float sig_fast(float x) { return rcp_fast(1.0f + __expf(-x)); }
__device__ __forceinline__ float tanh_fast(float x) {
    return 1.0f - 2.0f * rcp_fast(1.0f + __expf(2.0f * x));
}
__device__ __forceinline__ unsigned short f2bf(float x) {
    unsigned u = __float_as_uint(x);
    unsigned r = (u + 0x7FFFu + ((u >> 16) & 1u)) >> 16;  // RTN-even
    return (unsigned short)r;
}

// ---------------- resets dtype detector (bit1: f32 1.0 seen, bit2: u8-packed) --
__global__ void detect_resets_dtype(const unsigned int* __restrict__ r, int n,
                                    int* __restrict__ flag) {
    int bits = 0;
    for (int i = blockIdx.x * blockDim.x + threadIdx.x; i < n;
         i += gridDim.x * blockDim.x) {
        unsigned v = r[i];
        if (v == 0x3F800000u) bits |= 2;
        else if (v != 0u && v != 1u) bits |= 4;
    }
    if (bits) atomicOr(flag, bits);
}

__device__ __forceinline__ int decode_mode(const int* flag) {
    int fl = *flag;
    if ((fl & 2) && !(fl & 4)) return 2;   // float32
    if (fl & 4) return 1;                  // uint8
    return 0;                              // int32
}
__device__ __forceinline__ int load_rst(const void* resets, int mode, long idx) {
    if (mode == 1) return ((const unsigned char*)resets)[idx] != 0;
    if (mode == 2) return ((const float*)resets)[idx] != 0.0f;
    return ((const int*)resets)[idx] != 0;
}

// ---------------- Phase 1: Z = bias + ins @ Wi (transposed MFMA GEMM) ---------
// A[m=p][k] = Wi[k][(p&3)*64 + (p>>2)]   (16x32 tiles, m -> D row)
// B[k][n=bt] = ins[bt][k]                (n -> D col)
// D lane map (verified): col = lane&15, row = (lane>>4)*4 + reg
template<int ZBF>
__global__ __launch_bounds__(256, 2)
void zgemm_kernel(const float* __restrict__ ins, const float* __restrict__ Wi,
                  const float* __restrict__ bias, void* __restrict__ Zv) {
    const int lane = threadIdx.x & 63;
    const int w    = threadIdx.x >> 6;
    const int l15  = lane & 15;
    const int l4   = lane >> 4;
    const long bt0 = (long)blockIdx.x * 64;
    const int pbase = w * 64;

    short8 afr[4][2];
    f32x4  binit[4];
#pragma unroll
    for (int pt = 0; pt < 4; ++pt) {
        const int prow = pbase + pt * 16 + l15;
        const int n = (prow & 3) * 64 + (prow >> 2);
#pragma unroll
        for (int kc = 0; kc < 2; ++kc) {
            short8 f;
#pragma unroll
            for (int e = 0; e < 8; ++e) {
                const int k = kc * 32 + l4 * 8 + e;
                f[e] = (short)f2bf(Wi[k * NG + n]);
            }
            afr[pt][kc] = f;
        }
        f32x4 bi;
#pragma unroll
        for (int r = 0; r < 4; ++r) {
            const int pr = pbase + pt * 16 + l4 * 4 + r;
            const int n2 = (pr & 3) * 64 + (pr >> 2);
            bi[r] = bias[n2];
        }
        binit[pt] = bi;
    }

#pragma unroll
    for (int tt = 0; tt < 4; ++tt) {
        const long bt = bt0 + tt * 16 + l15;
        short8 bfr[2];
#pragma unroll
        for (int kc = 0; kc < 2; ++kc) {
            const float4* xp = (const float4*)(ins + bt * NF + kc * 32 + l4 * 8);
            float4 v0 = xp[0];
            float4 v1 = xp[1];
            short8 f;
            f[0] = (short)f2bf(v0.x); f[1] = (short)f2bf(v0.y);
            f[2] = (short)f2bf(v0.z); f[3] = (short)f2bf(v0.w);
            f[4] = (short)f2bf(v1.x); f[5] = (short)f2bf(v1.y);
            f[6] = (short)f2bf(v1.z); f[7] = (short)f2bf(v1.w);
            bfr[kc] = f;
        }
#pragma unroll
        for (int pt = 0; pt < 4; ++pt) {
            f32x4 acc = binit[pt];
            acc = __builtin_amdgcn_mfma_f32_16x16x32_bf16(afr[pt][0], bfr[0], acc, 0, 0, 0);
            acc = __builtin_amdgcn_mfma_f32_16x16x32_bf16(afr[pt][1], bfr[1], acc, 0, 0, 0);
            const int p0 = pbase + pt * 16 + l4 * 4;
            if (ZBF) {
                unsigned lo = (unsigned)f2bf(acc[0]) | ((unsigned)f2bf(acc[1]) << 16);
                unsigned hi = (unsigned)f2bf(acc[2]) | ((unsigned)f2bf(acc[3]) << 16);
                uint2* dst = (uint2*)((unsigned short*)Zv + bt * NG + p0);
                *dst = make_uint2(lo, hi);
            } else {
                f32x4* dst = (f32x4*)((float*)Zv + bt * NG + p0);
                *dst = acc;
            }
        }
    }
}

// ---------------- Phase 2: recurrence, one wave per batch row ----------------
template<int ZBF>
__global__ __launch_bounds__(64, 1)
void lstm_recur_kernel(const void* __restrict__ Zv, const void* __restrict__ resets,
                       const float* __restrict__ Wh, float* __restrict__ out,
                       const int* __restrict__ flag) {
    const int b = blockIdx.x;
    const int j = threadIdx.x;  // h-column 0..63
    const int mode = decode_mode(flag);

    float whi[NF], whf[NF], whg[NF], who[NF];
#pragma unroll
    for (int k = 0; k < NF; ++k) {
        whi[k] = Wh[k * NG + j];
        whf[k] = Wh[k * NG + NH + j];
        whg[k] = Wh[k * NG + 2 * NH + j];
        who[k] = Wh[k * NG + 3 * NH + j];
    }

    float h = 0.0f, c = 0.0f;
    const long base = (long)b * NT;

    // software-pipelined Z / reset loads
    float z0, z1, z2, z3;
    {
        if (ZBF) {
            const uint2 zz = *(const uint2*)((const unsigned short*)Zv + base * NG + j * 4);
            z0 = __uint_as_float(zz.x << 16);
            z1 = __uint_as_float(zz.x & 0xFFFF0000u);
            z2 = __uint_as_float(zz.y << 16);
            z3 = __uint_as_float(zz.y & 0xFFFF0000u);
        } else {
            const f32x4 zz = *(const f32x4*)((const float*)Zv + base * NG + j * 4);
            z0 = zz[0]; z1 = zz[1]; z2 = zz[2]; z3 = zz[3];
        }
    }
    int rc = load_rst(resets, mode, base);

    for (int t = 0; t < NT; ++t) {
        const long tn = base + (t + 1 < NT ? t + 1 : NT - 1);
        float n0, n1, n2, n3;
        if (ZBF) {
            const uint2 zz = *(const uint2*)((const unsigned short*)Zv + tn * NG + j * 4);
            n0 = __uint_as_float(zz.x << 16);
            n1 = __uint_as_float(zz.x & 0xFFFF0000u);
            n2 = __uint_as_float(zz.y << 16);
            n3 = __uint_as_float(zz.y & 0xFFFF0000u);
        } else {
            const f32x4 zz = *(const f32x4*)((const float*)Zv + tn * NG + j * 4);
            n0 = zz[0]; n1 = zz[1]; n2 = zz[2]; n3 = zz[3];
        }
        const int rn = load_rst(resets, mode, tn);

        float zi = z0, zf = z1, zg = z2, zo = z3;
        if (!rc) {  // wave-uniform; h==0 on reset -> skip h@Wh entirely
#pragma unroll
            for (int k = 0; k < NF; ++k) {
                const float hk = __uint_as_float(
                    (unsigned)__builtin_amdgcn_readlane(__float_as_uint(h), k));
                zi = fmaf(hk, whi[k], zi);
                zf = fmaf(hk, whf[k], zf);
                zg = fmaf(hk, whg[k], zg);
                zo = fmaf(hk, who[k], zo);
            }
        }
        const float ig = sig_fast(zi);
        const float fg = sig_fast(zf);
        const float gg = tanh_fast(zg);
        const float og = sig_fast(zo);
        const float cm = rc ? 0.0f : c;
        c = fmaf(fg, cm, ig * gg);
        h = og * tanh_fast(c);
        out[(base + t) * NH + j] = h;

        z0 = n0; z1 = n1; z2 = n2; z3 = n3;
        rc = rn;
    }
}

// ---------------- Fallback (R1 kernel, known-good) ---------------------------
__global__ __launch_bounds__(256, 2)
void lstm_scan_kernel(const float* __restrict__ ins, const void* __restrict__ resets,
                      const float* __restrict__ Wi, const float* __restrict__ Wh,
                      const float* __restrict__ bias, float* __restrict__ out,
                      const int* __restrict__ flag) {
    const int b = blockIdx.x;
    const int j = threadIdx.x;
    int mode = flag ? decode_mode(flag) : 0;

    float wi[NF], wh[NF];
#pragma unroll
    for (int k = 0; k < NF; ++k) {
        wi[k] = Wi[k * NG + j];
        wh[k] = Wh[k * NG + j];
    }
    const float bj = bias[j];

    __shared__ __align__(16) float xs[TCHUNK][NF];
    __shared__ int rs[TCHUNK];
    __shared__ __align__(16) float hbuf[2][NH];
    __shared__ float zbuf[NG];

    float c = 0.0f;
    if (j < NH) { hbuf[0][j] = 0.0f; hbuf[1][j] = 0.0f; }
    __syncthreads();

    int cur = 0;
    for (int t0 = 0; t0 < NT; t0 += TCHUNK) {
        {
            const float4* src = (const float4*)(ins + ((size_t)b * NT + t0) * NF);
            float4* dst = (float4*)&xs[0][0];
            dst[j] = src[j];
            dst[j + 256] = src[j + 256];
            if (j < TCHUNK) rs[j] = load_rst(resets, mode, (long)b * NT + t0 + j);
        }
        __syncthreads();

        for (int tt = 0; tt < TCHUNK; ++tt) {
            const int t = t0 + tt;
            const int rst = rs[tt];
            float accx = bj, acch = 0.0f;
            const float4* xv4 = (const float4*)&xs[tt][0];
#pragma unroll
            for (int k4 = 0; k4 < NF / 4; ++k4) {
                float4 xv = xv4[k4];
                accx = fmaf(xv.x, wi[4 * k4 + 0], accx);
                accx = fmaf(xv.y, wi[4 * k4 + 1], accx);
                accx = fmaf(xv.z, wi[4 * k4 + 2], accx);
                accx = fmaf(xv.w, wi[4 * k4 + 3], accx);
            }
            if (!rst) {
                const float4* hv4 = (const float4*)&hbuf[cur][0];
#pragma unroll
                for (int k4 = 0; k4 < NF / 4; ++k4) {
                    float4 hv = hv4[k4];
                    acch = fmaf(hv.x, wh[4 * k4 + 0], acch);
                    acch = fmaf(hv.y, wh[4 * k4 + 1], acch);
                    acch = fmaf(hv.z, wh[4 * k4 + 2], acch);
                    acch = fmaf(hv.w, wh[4 * k4 + 3], acch);
                }
            }
            zbuf[j] = accx + acch;
            __syncthreads();
            if (j < NH) {
                float zi = zbuf[j], zf = zbuf[j + NH], zg = zbuf[j + 2 * NH], zo = zbuf[j + 3 * NH];
                float ig = sig_fast(zi), fg = sig_fast(zf), gg = tanh_fast(zg), og = sig_fast(zo);
                float cc = rst ? 0.0f : c;
                cc = fg * cc + ig * gg;
                c = cc;
                float hh = og * tanh_fast(cc);
                hbuf[cur ^ 1][j] = hh;
                out[((size_t)b * NT + t) * NH + j] = hh;
            }
            __syncthreads();
            cur ^= 1;
        }
    }
}

extern "C" void kernel_launch(void* const* d_in, const int* in_sizes, int n_in,
                              void* d_out, int out_size, void* d_ws, size_t ws_size,
                              hipStream_t stream) {
    const float* ins    = (const float*)d_in[0];
    const void*  resets = d_in[1];
    const float* Wi     = (const float*)d_in[2];
    const float* Wh     = (const float*)d_in[3];
    const float* bias   = (const float*)d_in[4];
    float* out = (float*)d_out;

    const size_t ZF32  = (size_t)NB * NT * NG * 4;  // 268 MB
    const size_t ZBF16 = ZF32 / 2;                  // 134 MB
    const int nBT = NB * NT;

    if (ws_size >= ZF32 + 64) {
        int* flag = (int*)((char*)d_ws + ZF32);
        hipMemsetAsync(flag, 0, sizeof(int), stream);
        detect_resets_dtype<<<256, 256, 0, stream>>>((const unsigned int*)resets, nBT, flag);
        zgemm_kernel<0><<<nBT / 64, 256, 0, stream>>>(ins, Wi, bias, d_ws);
        lstm_recur_kernel<0><<<NB, 64, 0, stream>>>(d_ws, resets, Wh, out, flag);
    } else if (ws_size >= ZBF16 + 64) {
        int* flag = (int*)((char*)d_ws + ZBF16);
        hipMemsetAsync(flag, 0, sizeof(int), stream);
        detect_resets_dtype<<<256, 256, 0, stream>>>((const unsigned int*)resets, nBT, flag);
        zgemm_kernel<1><<<nBT / 64, 256, 0, stream>>>(ins, Wi, bias, d_ws);
        lstm_recur_kernel<1><<<NB, 64, 0, stream>>>(d_ws, resets, Wh, out, flag);
    } else {
        int* flag = nullptr;
        if (d_ws && ws_size >= sizeof(int)) {
            flag = (int*)d_ws;
            hipMemsetAsync(flag, 0, sizeof(int), stream);
            detect_resets_dtype<<<256, 256, 0, stream>>>((const unsigned int*)resets, nBT, flag);
        }
        lstm_scan_kernel<<<NB, 256, 0, stream>>>(ins, resets, Wi, Wh, bias, out, flag);
    }
}

// Round 3
// 453.206 us; speedup vs baseline: 1.2215x; 1.2215x over previous
//
#include <hip/hip_runtime.h>

// ScannedLSTM: B=512, T=512, F=64, H=64 (4H=256)
// Phase 1 (zgemm2): Z[bt][n] = bias[n] + x[bt]@Wi[:,n], bf16, natural gate
//   order n = gate*64 + col. MFMA 16x16x32_bf16, x staged via padded LDS.
// Phase 2 (lstm_recur2): 1 block per batch row, 4 waves = 4 gates.
//   Lane j of wave w owns gate column p = w*64+j: 64 Wh floats in registers.
//   Per step: s = Z[t][p] + sum_k h[k]*wh[k] (h via LDS float4 broadcast,
//   per-wave replicated copy), z exchanged through LDS (1 barrier/step),
//   gates+c+h computed redundantly in all 4 waves. Reset skips the FMA loop.

typedef __attribute__((ext_vector_type(8))) short short8;
typedef __attribute__((ext_vector_type(4))) float f32x4;

#define NB 512
#define NT 512
#define NF 64
#define NH 64
#define NG 256
#define TCHUNK 32

__device__ __forceinline__ float rcp_fast(float x) { return __builtin_amdgcn_rcpf(x); }
__device__ __forceinline__ float sig_fast(float x) { return rcp_fast(1.0f + __expf(-x)); }
__device__ __forceinline__ float tanh_fast(float x) {
    return 1.0f - 2.0f * rcp_fast(1.0f + __expf(2.0f * x));
}
__device__ __forceinline__ unsigned short f2bf(float x) {
    unsigned u = __float_as_uint(x);
    return (unsigned short)((u + 0x7FFFu + ((u >> 16) & 1u)) >> 16);  // RTN-even
}
__device__ __forceinline__ float bf2f(unsigned short s) {
    return __uint_as_float(((unsigned)s) << 16);
}

// ---- resets dtype detector (bit1: f32 1.0 seen, bit2: u8-packed values) -----
__global__ void detect_resets_dtype(const unsigned int* __restrict__ r, int n,
                                    int* __restrict__ flag) {
    int bits = 0;
    for (int i = blockIdx.x * blockDim.x + threadIdx.x; i < n;
         i += gridDim.x * blockDim.x) {
        unsigned v = r[i];
        if (v == 0x3F800000u) bits |= 2;
        else if (v != 0u && v != 1u) bits |= 4;
    }
    if (bits) atomicOr(flag, bits);
}
__device__ __forceinline__ int decode_mode(const int* flag) {
    int fl = *flag;
    if ((fl & 2) && !(fl & 4)) return 2;   // float32
    if (fl & 4) return 1;                  // uint8
    return 0;                              // int32
}
__device__ __forceinline__ int load_rst(const void* resets, int mode, long idx) {
    if (mode == 1) return ((const unsigned char*)resets)[idx] != 0;
    if (mode == 2) return ((const float*)resets)[idx] != 0.0f;
    return ((const int*)resets)[idx] != 0;
}

// ---------------- Phase 1: Z(bf16) = bias + ins @ Wi -------------------------
// D lane map (verified R2): col = lane&15 -> bt, row = (lane>>4)*4+reg -> n.
__global__ __launch_bounds__(256, 2)
void zgemm2(const float* __restrict__ ins, const float* __restrict__ Wi,
            const float* __restrict__ bias, unsigned short* __restrict__ Z) {
    const int tid = threadIdx.x;
    const int lane = tid & 63;
    const int w = tid >> 6;
    const int l15 = lane & 15, l4 = lane >> 4;
    const long bt0 = (long)blockIdx.x * 64;
    const int nbase = w << 6;

    __shared__ __align__(16) float xs[64][68];  // +4 pad: conflict-free reads

    {   // stage 64 bt-rows x 64 f32, fully coalesced (4 float4 per thread)
        const float4* src = (const float4*)(ins + bt0 * NF);
#pragma unroll
        for (int i = 0; i < 4; ++i) {
            const int q = tid + 256 * i;
            const int row = q >> 4, c4 = (q & 15) << 2;
            *(float4*)&xs[row][c4] = src[q];
        }
    }

    short8 afr[4][2];
    f32x4 binit[4];
#pragma unroll
    for (int pt = 0; pt < 4; ++pt) {
        const int n = nbase + pt * 16 + l15;
#pragma unroll
        for (int kc = 0; kc < 2; ++kc) {
            short8 f;
#pragma unroll
            for (int e = 0; e < 8; ++e)
                f[e] = (short)f2bf(Wi[(kc * 32 + l4 * 8 + e) * NG + n]);
            afr[pt][kc] = f;
        }
        f32x4 bi;
#pragma unroll
        for (int r = 0; r < 4; ++r) bi[r] = bias[nbase + pt * 16 + l4 * 4 + r];
        binit[pt] = bi;
    }
    __syncthreads();

#pragma unroll
    for (int tt = 0; tt < 4; ++tt) {
        short8 bfr[2];
#pragma unroll
        for (int kc = 0; kc < 2; ++kc) {
            const float* rp = &xs[tt * 16 + l15][kc * 32 + l4 * 8];
            const float4 v0 = *(const float4*)rp;
            const float4 v1 = *(const float4*)(rp + 4);
            short8 f;
            f[0] = (short)f2bf(v0.x); f[1] = (short)f2bf(v0.y);
            f[2] = (short)f2bf(v0.z); f[3] = (short)f2bf(v0.w);
            f[4] = (short)f2bf(v1.x); f[5] = (short)f2bf(v1.y);
            f[6] = (short)f2bf(v1.z); f[7] = (short)f2bf(v1.w);
            bfr[kc] = f;
        }
        const long bt = bt0 + tt * 16 + l15;
#pragma unroll
        for (int pt = 0; pt < 4; ++pt) {
            f32x4 acc = binit[pt];
            acc = __builtin_amdgcn_mfma_f32_16x16x32_bf16(afr[pt][0], bfr[0], acc, 0, 0, 0);
            acc = __builtin_amdgcn_mfma_f32_16x16x32_bf16(afr[pt][1], bfr[1], acc, 0, 0, 0);
            unsigned lo = (unsigned)f2bf(acc[0]) | ((unsigned)f2bf(acc[1]) << 16);
            unsigned hi = (unsigned)f2bf(acc[2]) | ((unsigned)f2bf(acc[3]) << 16);
            *(uint2*)&Z[bt * NG + nbase + pt * 16 + l4 * 4] = make_uint2(lo, hi);
        }
    }
}

// ---------------- Phase 2: gate-split recurrence -----------------------------
__global__ __launch_bounds__(256, 2)
void lstm_recur2(const unsigned short* __restrict__ Z, const void* __restrict__ resets,
                 const float* __restrict__ Wh, float* __restrict__ out,
                 const int* __restrict__ flag) {
    const int tid = threadIdx.x;
    const int w = tid >> 6;          // gate 0..3 (i,f,g,o)
    const int j = tid & 63;          // h column
    const int p = (w << 6) + j;      // z column
    const int b = blockIdx.x;
    const int mode = decode_mode(flag);
    const long base = (long)b * NT;

    float wh[NF];                    // 64 regs: Wh[:, p]
#pragma unroll
    for (int k = 0; k < NF; ++k) wh[k] = Wh[k * NG + p];

    __shared__ float zx[2][NG];                      // z exchange, dbuf
    __shared__ __align__(16) float hsh[4][2][NH];    // per-wave h copy, dbuf

    hsh[w][0][j] = 0.0f;
    __syncthreads();

    float c = 0.0f;
    int cb = 0;

#define LCLAMP(T) (base + (((T) < NT - 1) ? (T) : (NT - 1)))

    // prefetch: group A = t0..t0+3, group B = t0+4..t0+7 (distance 4-8 steps)
    unsigned short zA0, zA1, zA2, zA3, zB0, zB1, zB2, zB3;
    int rA0, rA1, rA2, rA3, rB0, rB1, rB2, rB3;
    zA0 = Z[(base + 0) * NG + p]; zA1 = Z[(base + 1) * NG + p];
    zA2 = Z[(base + 2) * NG + p]; zA3 = Z[(base + 3) * NG + p];
    rA0 = load_rst(resets, mode, base + 0); rA1 = load_rst(resets, mode, base + 1);
    rA2 = load_rst(resets, mode, base + 2); rA3 = load_rst(resets, mode, base + 3);
    zB0 = Z[(base + 4) * NG + p]; zB1 = Z[(base + 5) * NG + p];
    zB2 = Z[(base + 6) * NG + p]; zB3 = Z[(base + 7) * NG + p];
    rB0 = load_rst(resets, mode, base + 4); rB1 = load_rst(resets, mode, base + 5);
    rB2 = load_rst(resets, mode, base + 6); rB3 = load_rst(resets, mode, base + 7);

#define STEP(T, ZPRE, RST) do {                                                \
        float s = (ZPRE);                                                      \
        if (!(RST)) {                                                          \
            const f32x4* hp = (const f32x4*)&hsh[w][cb][0];                    \
            float s0 = 0.f, s1 = 0.f, s2 = 0.f, s3 = 0.f;                      \
            _Pragma("unroll")                                                  \
            for (int k16 = 0; k16 < 4; ++k16) {                                \
                const f32x4 ha = hp[k16 * 4 + 0];                              \
                const f32x4 hb = hp[k16 * 4 + 1];                              \
                const f32x4 hc = hp[k16 * 4 + 2];                              \
                const f32x4 hd = hp[k16 * 4 + 3];                              \
                s0 = fmaf(ha[0], wh[k16 * 16 + 0], s0);                        \
                s0 = fmaf(ha[1], wh[k16 * 16 + 1], s0);                        \
                s0 = fmaf(ha[2], wh[k16 * 16 + 2], s0);                        \
                s0 = fmaf(ha[3], wh[k16 * 16 + 3], s0);                        \
                s1 = fmaf(hb[0], wh[k16 * 16 + 4], s1);                        \
                s1 = fmaf(hb[1], wh[k16 * 16 + 5], s1);                        \
                s1 = fmaf(hb[2], wh[k16 * 16 + 6], s1);                        \
                s1 = fmaf(hb[3], wh[k16 * 16 + 7], s1);                        \
                s2 = fmaf(hc[0], wh[k16 * 16 + 8], s2);                        \
                s2 = fmaf(hc[1], wh[k16 * 16 + 9], s2);                        \
                s2 = fmaf(hc[2], wh[k16 * 16 + 10], s2);                       \
                s2 = fmaf(hc[3], wh[k16 * 16 + 11], s2);                       \
                s3 = fmaf(hd[0], wh[k16 * 16 + 12], s3);                       \
                s3 = fmaf(hd[1], wh[k16 * 16 + 13], s3);                       \
                s3 = fmaf(hd[2], wh[k16 * 16 + 14], s3);                       \
                s3 = fmaf(hd[3], wh[k16 * 16 + 15], s3);                       \
            }                                                                  \
            s += (s0 + s1) + (s2 + s3);                                        \
        }                                                                      \
        zx[cb][p] = s;                                                         \
        __syncthreads();                                                       \
        const float zi = zx[cb][j];                                            \
        const float zf = zx[cb][NH + j];                                       \
        const float zg = zx[cb][2 * NH + j];                                   \
        const float zo = zx[cb][3 * NH + j];                                   \
        const float ig = sig_fast(zi);                                         \
        const float fg = sig_fast(zf);                                         \
        const float gg = tanh_fast(zg);                                        \
        const float og = sig_fast(zo);                                         \
        const float cm = (RST) ? 0.0f : c;                                     \
        c = fmaf(fg, cm, ig * gg);                                             \
        const float hv = og * tanh_fast(c);                                    \
        hsh[w][cb ^ 1][j] = hv;                                                \
        if (w == 0) out[(base + (T)) * NH + j] = hv;                           \
        cb ^= 1;                                                               \
    } while (0)

    for (int t0 = 0; t0 < NT; t0 += 8) {
        // consume A into locals, then refill A for t0+8 (prefetch dist 4-8)
        const float fA0 = bf2f(zA0), fA1 = bf2f(zA1), fA2 = bf2f(zA2), fA3 = bf2f(zA3);
        const int qA0 = rA0, qA1 = rA1, qA2 = rA2, qA3 = rA3;
        {
            const long i0 = LCLAMP(t0 + 8), i1 = LCLAMP(t0 + 9);
            const long i2 = LCLAMP(t0 + 10), i3 = LCLAMP(t0 + 11);
            zA0 = Z[i0 * NG + p]; zA1 = Z[i1 * NG + p];
            zA2 = Z[i2 * NG + p]; zA3 = Z[i3 * NG + p];
            rA0 = load_rst(resets, mode, i0); rA1 = load_rst(resets, mode, i1);
            rA2 = load_rst(resets, mode, i2); rA3 = load_rst(resets, mode, i3);
        }
        STEP(t0 + 0, fA0, qA0); STEP(t0 + 1, fA1, qA1);
        STEP(t0 + 2, fA2, qA2); STEP(t0 + 3, fA3, qA3);

        const float fB0 = bf2f(zB0), fB1 = bf2f(zB1), fB2 = bf2f(zB2), fB3 = bf2f(zB3);
        const int qB0 = rB0, qB1 = rB1, qB2 = rB2, qB3 = rB3;
        {
            const long i0 = LCLAMP(t0 + 12), i1 = LCLAMP(t0 + 13);
            const long i2 = LCLAMP(t0 + 14), i3 = LCLAMP(t0 + 15);
            zB0 = Z[i0 * NG + p]; zB1 = Z[i1 * NG + p];
            zB2 = Z[i2 * NG + p]; zB3 = Z[i3 * NG + p];
            rB0 = load_rst(resets, mode, i0); rB1 = load_rst(resets, mode, i1);
            rB2 = load_rst(resets, mode, i2); rB3 = load_rst(resets, mode, i3);
        }
        STEP(t0 + 4, fB0, qB0); STEP(t0 + 5, fB1, qB1);
        STEP(t0 + 6, fB2, qB2); STEP(t0 + 7, fB3, qB3);
    }
#undef STEP
#undef LCLAMP
}

// ---------------- Fallback (R1 kernel, known-good) ---------------------------
__global__ __launch_bounds__(256, 2)
void lstm_scan_kernel(const float* __restrict__ ins, const void* __restrict__ resets,
                      const float* __restrict__ Wi, const float* __restrict__ Wh,
                      const float* __restrict__ bias, float* __restrict__ out,
                      const int* __restrict__ flag) {
    const int b = blockIdx.x;
    const int j = threadIdx.x;
    int mode = flag ? decode_mode(flag) : 0;

    float wi[NF], wh[NF];
#pragma unroll
    for (int k = 0; k < NF; ++k) {
        wi[k] = Wi[k * NG + j];
        wh[k] = Wh[k * NG + j];
    }
    const float bj = bias[j];

    __shared__ __align__(16) float xs[TCHUNK][NF];
    __shared__ int rs[TCHUNK];
    __shared__ __align__(16) float hbuf[2][NH];
    __shared__ float zbuf[NG];

    float c = 0.0f;
    if (j < NH) { hbuf[0][j] = 0.0f; hbuf[1][j] = 0.0f; }
    __syncthreads();

    int cur = 0;
    for (int t0 = 0; t0 < NT; t0 += TCHUNK) {
        {
            const float4* src = (const float4*)(ins + ((size_t)b * NT + t0) * NF);
            float4* dst = (float4*)&xs[0][0];
            dst[j] = src[j];
            dst[j + 256] = src[j + 256];
            if (j < TCHUNK) rs[j] = load_rst(resets, mode, (long)b * NT + t0 + j);
        }
        __syncthreads();

        for (int tt = 0; tt < TCHUNK; ++tt) {
            const int t = t0 + tt;
            const int rst = rs[tt];
            float accx = bj, acch = 0.0f;
            const float4* xv4 = (const float4*)&xs[tt][0];
#pragma unroll
            for (int k4 = 0; k4 < NF / 4; ++k4) {
                float4 xv = xv4[k4];
                accx = fmaf(xv.x, wi[4 * k4 + 0], accx);
                accx = fmaf(xv.y, wi[4 * k4 + 1], accx);
                accx = fmaf(xv.z, wi[4 * k4 + 2], accx);
                accx = fmaf(xv.w, wi[4 * k4 + 3], accx);
            }
            if (!rst) {
                const float4* hv4 = (const float4*)&hbuf[cur][0];
#pragma unroll
                for (int k4 = 0; k4 < NF / 4; ++k4) {
                    float4 hv = hv4[k4];
                    acch = fmaf(hv.x, wh[4 * k4 + 0], acch);
                    acch = fmaf(hv.y, wh[4 * k4 + 1], acch);
                    acch = fmaf(hv.z, wh[4 * k4 + 2], acch);
                    acch = fmaf(hv.w, wh[4 * k4 + 3], acch);
                }
            }
            zbuf[j] = accx + acch;
            __syncthreads();
            if (j < NH) {
                float zi = zbuf[j], zf = zbuf[j + NH], zg = zbuf[j + 2 * NH], zo = zbuf[j + 3 * NH];
                float ig = sig_fast(zi), fg = sig_fast(zf), gg = tanh_fast(zg), og = sig_fast(zo);
                float cc = rst ? 0.0f : c;
                cc = fg * cc + ig * gg;
                c = cc;
                float hh = og * tanh_fast(cc);
                hbuf[cur ^ 1][j] = hh;
                out[((size_t)b * NT + t) * NH + j] = hh;
            }
            __syncthreads();
            cur ^= 1;
        }
    }
}

extern "C" void kernel_launch(void* const* d_in, const int* in_sizes, int n_in,
                              void* d_out, int out_size, void* d_ws, size_t ws_size,
                              hipStream_t stream) {
    const float* ins    = (const float*)d_in[0];
    const void*  resets = d_in[1];
    const float* Wi     = (const float*)d_in[2];
    const float* Wh     = (const float*)d_in[3];
    const float* bias   = (const float*)d_in[4];
    float* out = (float*)d_out;

    const size_t ZBF16 = (size_t)NB * NT * NG * 2;  // 134 MB
    const int nBT = NB * NT;

    if (ws_size >= ZBF16 + 64) {
        int* flag = (int*)((char*)d_ws + ZBF16);
        hipMemsetAsync(flag, 0, sizeof(int), stream);
        detect_resets_dtype<<<256, 256, 0, stream>>>((const unsigned int*)resets, nBT, flag);
        zgemm2<<<nBT / 64, 256, 0, stream>>>(ins, Wi, bias, (unsigned short*)d_ws);
        lstm_recur2<<<NB, 256, 0, stream>>>((const unsigned short*)d_ws, resets, Wh, out, flag);
    } else {
        int* flag = nullptr;
        if (d_ws && ws_size >= sizeof(int)) {
            flag = (int*)d_ws;
            hipMemsetAsync(flag, 0, sizeof(int), stream);
            detect_resets_dtype<<<256, 256, 0, stream>>>((const unsigned int*)resets, nBT, flag);
        }
        lstm_scan_kernel<<<NB, 256, 0, stream>>>(ins, resets, Wi, Wh, bias, out, flag);
    }
}